// Round 6
// baseline (388.984 us; speedup 1.0000x reference)
//
#include <hip/hip_runtime.h>
#include <hip/hip_bf16.h>

typedef __bf16 bf16;
typedef __bf16 bf16x4 __attribute__((ext_vector_type(4)));
typedef __bf16 bf16x8 __attribute__((ext_vector_type(8)));
typedef float f32x4 __attribute__((ext_vector_type(4)));

#define MFMA16(a, b, c) __builtin_amdgcn_mfma_f32_16x16x32_bf16(a, b, c, 0, 0, 0)

constexpr int DIM = 1024;
constexpr int NH = 16;
constexpr int HD = 64;
constexpr float SCALE = 0.125f;
constexpr float L2E = 1.4426950408889634f;
constexpr float SCL2E = SCALE * L2E;  // folded into Q-proj epilogue

constexpr int ilog2(int v) {
  int s = 0;
  while ((1 << s) < v) ++s;
  return s;
}

// raw v_exp_f32 — bypass the denorm-guarded exp2f lowering
__device__ __forceinline__ float fast_exp2(float x) {
  float r;
  asm("v_exp_f32 %0, %1" : "=v"(r) : "v"(x));
  return r;
}

// async global->LDS, 16B per lane; lane i deposits at ldsbase + i*16
__device__ __forceinline__ void gl_lds16(const void* g, void* l) {
  __builtin_amdgcn_global_load_lds((const __attribute__((address_space(1))) void*)g,
                                   (__attribute__((address_space(3))) void*)l, 16, 0, 0);
}

// ---------------------------------------------------------------------------
// fp32 -> bf16 conversion (memory-bound, vectorized 8/thread)
// ---------------------------------------------------------------------------
__global__ __launch_bounds__(256) void cvt_f32_bf16(const float* __restrict__ s,
                                                    bf16* __restrict__ d, int n8) {
  const int i = blockIdx.x * 256 + threadIdx.x;
  if (i < n8) {
    const float4 v0 = ((const float4*)s)[i * 2];
    const float4 v1 = ((const float4*)s)[i * 2 + 1];
    bf16x8 o = {(bf16)v0.x, (bf16)v0.y, (bf16)v0.z, (bf16)v0.w,
                (bf16)v1.x, (bf16)v1.y, (bf16)v1.z, (bf16)v1.w};
    ((bf16x8*)d)[i] = o;
  }
}

// all 4 weight matrices in one launch; dst regions are contiguous in ws
__global__ __launch_bounds__(256) void cvt_w4(const float* __restrict__ a,
                                              const float* __restrict__ b,
                                              const float* __restrict__ c,
                                              const float* __restrict__ d,
                                              bf16* __restrict__ o) {
  constexpr int N8 = DIM * DIM / 8;  // 131072 (pow2)
  const int i = blockIdx.x * 256 + threadIdx.x;  // grid covers 4*N8 exactly
  const int g = i >> 17;
  const int j = i & (N8 - 1);
  const float* s = (g == 0) ? a : (g == 1) ? b : (g == 2) ? c : d;
  const float4 v0 = ((const float4*)s)[j * 2];
  const float4 v1 = ((const float4*)s)[j * 2 + 1];
  bf16x8 ov = {(bf16)v0.x, (bf16)v0.y, (bf16)v0.z, (bf16)v0.w,
               (bf16)v1.x, (bf16)v1.y, (bf16)v1.z, (bf16)v1.w};
  ((bf16x8*)o)[i] = ov;
}

// ---------------------------------------------------------------------------
// BIG bf16 NT GEMM for M=16384 (Q-proj / O-proj) — m201-style phased schedule.
// 256x256 tile, BK=64 split in two 32-col halves, 512 thr (8 waves, 2M x 4N:
// per-wave C = 128 rows x 64 cols). Per K-tile: 4 phases, each
//   {ds_read A-frag pair -> barrier -> lgkmcnt(0) -> setprio(1) -> 16 MFMA}.
// B-frags (8) read once in phase 0 and held in registers across phases.
// Double-buffered K-tiles; stage(t+2) issued at phase 3 AFTER a drain-ordered
// barrier (all waves' reads of this buffer complete -> overwrite safe).
// Counted vmcnt(8) at iter end (never 0 until the pipeline drains).
// LDS layout per matrix: [buf][khalf][256 rows][32 cols], 64 B rows; 16B chunk
// q of row r stored at slot q ^ (r&3) -> frag reads hit 64 distinct slots
// (conflict-free, verified structure in R5).
// ---------------------------------------------------------------------------
template <int OUT_MODE, int LQ>  // 0: fp32 row-major; 1: bf16 head-major
__global__ __launch_bounds__(512, 2) void gemm_big(const bf16* __restrict__ A,
                                                   const bf16* __restrict__ W,
                                                   const float* __restrict__ bias,
                                                   void* __restrict__ Cptr,
                                                   float oscale) {
  constexpr int LQS = ilog2(LQ);
  constexpr int NT = DIM / 64;  // 16 K-tiles
  __shared__ bf16 AS[2][2][256 * 32];  // [buf][khalf][row*32+col]  64 KiB
  __shared__ bf16 BS[2][2][256 * 32];  //                           64 KiB

  const int bm = blockIdx.x * 256;
  const int bn = blockIdx.y * 256;
  const int tid = threadIdx.x;
  const int w = tid >> 6;
  const int lane = tid & 63;
  const int quad = lane >> 4;
  const int l16 = lane & 15;
  const int lr4 = lane >> 2;                      // 0..15
  const int sc = ((lane & 3) ^ (lr4 & 3)) << 3;   // swizzled src chunk (elems)
  const int rowBase = (w >> 2) * 128;             // wave M offset (2 waves)
  const int colBase = (w & 3) * 64;               // wave N offset (4 waves)
  const int swz = (quad ^ (l16 & 3)) << 4;        // frag-read swizzle (bytes)

  // per-lane global row bases for staging (+ hf*128 rows, + t*64 + k*32 cols)
  const size_t aRow = (size_t)(bm + w * 16 + lr4) * DIM + sc;
  const size_t bRow = (size_t)(bn + w * 16 + lr4) * DIM + sc;

  auto stage = [&](int t, int c) {
#pragma unroll
    for (int i = 0; i < 4; ++i) {
      const int k = i >> 1, hf = i & 1;
      const size_t off = (size_t)(hf * 128) * DIM + t * 64 + k * 32;
      gl_lds16(A + aRow + off, (char*)&AS[c][k][0] + hf * 8192 + w * 1024);
      gl_lds16(W + bRow + off, (char*)&BS[c][k][0] + hf * 8192 + w * 1024);
    }
  };

  f32x4 acc[4][8] = {};  // [ni][mi]

  stage(0, 0);
  stage(1, 1);
  asm volatile("s_waitcnt vmcnt(8)" ::: "memory");  // tile 0 resident
  __builtin_amdgcn_s_barrier();

  int c = 0;
  for (int t = 0; t < NT; ++t) {
    const char* A0 = (const char*)&AS[c][0][0];
    const char* A1 = (const char*)&AS[c][1][0];
    const char* B0 = (const char*)&BS[c][0][0];
    const char* B1 = (const char*)&BS[c][1][0];
    const int aB = (rowBase + l16) * 64 + swz;
    const int bB = (colBase + l16) * 64 + swz;

    // ---- phase 0: all B-frags (held in regs) + A-frags mi{0,1}
    bf16x8 bf0[4], bf1[4];
#pragma unroll
    for (int ni = 0; ni < 4; ++ni) {
      bf0[ni] = *(const bf16x8*)(B0 + bB + ni * 1024);
      bf1[ni] = *(const bf16x8*)(B1 + bB + ni * 1024);
    }
    bf16x8 a0k0 = *(const bf16x8*)(A0 + aB + 0 * 1024);
    bf16x8 a0k1 = *(const bf16x8*)(A1 + aB + 0 * 1024);
    bf16x8 a1k0 = *(const bf16x8*)(A0 + aB + 1 * 1024);
    bf16x8 a1k1 = *(const bf16x8*)(A1 + aB + 1 * 1024);
    __builtin_amdgcn_s_barrier();
    asm volatile("s_waitcnt lgkmcnt(0)" ::: "memory");
    __builtin_amdgcn_s_setprio(1);
#pragma unroll
    for (int ni = 0; ni < 4; ++ni) {
      acc[ni][0] = MFMA16(a0k0, bf0[ni], acc[ni][0]);
      acc[ni][0] = MFMA16(a0k1, bf1[ni], acc[ni][0]);
      acc[ni][1] = MFMA16(a1k0, bf0[ni], acc[ni][1]);
      acc[ni][1] = MFMA16(a1k1, bf1[ni], acc[ni][1]);
    }
    __builtin_amdgcn_s_setprio(0);

    // ---- phase 1: mi{2,3}
    a0k0 = *(const bf16x8*)(A0 + aB + 2 * 1024);
    a0k1 = *(const bf16x8*)(A1 + aB + 2 * 1024);
    a1k0 = *(const bf16x8*)(A0 + aB + 3 * 1024);
    a1k1 = *(const bf16x8*)(A1 + aB + 3 * 1024);
    __builtin_amdgcn_s_barrier();
    asm volatile("s_waitcnt lgkmcnt(0)" ::: "memory");
    __builtin_amdgcn_s_setprio(1);
#pragma unroll
    for (int ni = 0; ni < 4; ++ni) {
      acc[ni][2] = MFMA16(a0k0, bf0[ni], acc[ni][2]);
      acc[ni][2] = MFMA16(a0k1, bf1[ni], acc[ni][2]);
      acc[ni][3] = MFMA16(a1k0, bf0[ni], acc[ni][3]);
      acc[ni][3] = MFMA16(a1k1, bf1[ni], acc[ni][3]);
    }
    __builtin_amdgcn_s_setprio(0);

    // ---- phase 2: mi{4,5}
    a0k0 = *(const bf16x8*)(A0 + aB + 4 * 1024);
    a0k1 = *(const bf16x8*)(A1 + aB + 4 * 1024);
    a1k0 = *(const bf16x8*)(A0 + aB + 5 * 1024);
    a1k1 = *(const bf16x8*)(A1 + aB + 5 * 1024);
    __builtin_amdgcn_s_barrier();
    asm volatile("s_waitcnt lgkmcnt(0)" ::: "memory");
    __builtin_amdgcn_s_setprio(1);
#pragma unroll
    for (int ni = 0; ni < 4; ++ni) {
      acc[ni][4] = MFMA16(a0k0, bf0[ni], acc[ni][4]);
      acc[ni][4] = MFMA16(a0k1, bf1[ni], acc[ni][4]);
      acc[ni][5] = MFMA16(a1k0, bf0[ni], acc[ni][5]);
      acc[ni][5] = MFMA16(a1k1, bf1[ni], acc[ni][5]);
    }
    __builtin_amdgcn_s_setprio(0);

    // ---- phase 3: mi{6,7}; drain reads BEFORE barrier so the post-barrier
    // stage(t+2) overwrite of this buffer is race-free block-wide.
    a0k0 = *(const bf16x8*)(A0 + aB + 6 * 1024);
    a0k1 = *(const bf16x8*)(A1 + aB + 6 * 1024);
    a1k0 = *(const bf16x8*)(A0 + aB + 7 * 1024);
    a1k1 = *(const bf16x8*)(A1 + aB + 7 * 1024);
    asm volatile("s_waitcnt lgkmcnt(0)" ::: "memory");
    __builtin_amdgcn_s_barrier();
    if (t + 2 < NT) stage(t + 2, c);
    __builtin_amdgcn_s_setprio(1);
#pragma unroll
    for (int ni = 0; ni < 4; ++ni) {
      acc[ni][6] = MFMA16(a0k0, bf0[ni], acc[ni][6]);
      acc[ni][6] = MFMA16(a0k1, bf1[ni], acc[ni][6]);
      acc[ni][7] = MFMA16(a1k0, bf0[ni], acc[ni][7]);
      acc[ni][7] = MFMA16(a1k1, bf1[ni], acc[ni][7]);
    }
    __builtin_amdgcn_s_setprio(0);

    // ---- iter end: wait next tile (counted — stage(t+2) stays in flight)
    if (t < NT - 2) {
      asm volatile("s_waitcnt vmcnt(8)" ::: "memory");
    } else if (t == NT - 2) {
      asm volatile("s_waitcnt vmcnt(0)" ::: "memory");
    }
    if (t < NT - 1) __builtin_amdgcn_s_barrier();
    c ^= 1;
  }

  // ---- epilogue (fragment->C mapping verified in R5)
  float bcol[4];
#pragma unroll
  for (int ni = 0; ni < 4; ++ni) bcol[ni] = bias[bn + colBase + ni * 16 + l16];

#pragma unroll
  for (int ni = 0; ni < 4; ++ni) {
    const int col = bn + colBase + ni * 16 + l16;
#pragma unroll
    for (int mi = 0; mi < 8; ++mi) {
#pragma unroll
      for (int r = 0; r < 4; ++r) {
        const int row = bm + rowBase + mi * 16 + quad * 4 + r;
        const float val = (acc[ni][mi][r] + bcol[ni]) * oscale;
        if constexpr (OUT_MODE == 0) {
          ((float*)Cptr)[(size_t)row * DIM + col] = val;
        } else {
          const int b = row >> LQS;
          const int l = row & (LQ - 1);
          ((bf16*)Cptr)[((((size_t)(b * NH + (col >> 6)) << LQS) + l) << 6) +
                        (col & 63)] = (bf16)val;
        }
      }
    }
  }
}

// ---------------------------------------------------------------------------
// bf16 NT GEMM, m97 structure (128^2): kept for the small-M K/V projections.
// OUT_MODE 1: bf16 head-major; 3: V^T flipped orientation (bias by ROW).
// ---------------------------------------------------------------------------
template <int OUT_MODE, int LQ>
__global__ __launch_bounds__(256) void gemm_bf16(const bf16* __restrict__ A,
                                                 const bf16* __restrict__ W,
                                                 const float* __restrict__ bias,
                                                 void* __restrict__ Cptr,
                                                 float oscale) {
  constexpr int LQS = ilog2(LQ);
  __shared__ bf16 As[128 * 64];
  __shared__ bf16 Bs[128 * 64];

  const int bm = blockIdx.x * 128;
  const int bn = blockIdx.y * 128;
  const int tid = threadIdx.x;
  const int w = tid >> 6;
  const int lane = tid & 63;
  const int quad = lane >> 4;
  const int l16 = lane & 15;
  const int wm = (w >> 1) * 64;
  const int wn = (w & 1) * 64;
  const int lr = lane >> 3;
  const int sc8 = (((lane & 7) ^ lr)) << 3;
  const int x7 = l16 & 7;

  size_t aOff[4], bOff[4];
#pragma unroll
  for (int r = 0; r < 4; ++r) {
    const int rowt = (r * 4 + w) * 8 + lr;
    aOff[r] = (size_t)(bm + rowt) * DIM + sc8;
    bOff[r] = (size_t)(bn + rowt) * DIM + sc8;
  }

  f32x4 acc[4][4] = {};

  for (int k0 = 0; k0 < DIM; k0 += 64) {
#pragma unroll
    for (int r = 0; r < 4; ++r) {
      gl_lds16(A + aOff[r] + k0, (char*)As + (r * 4 + w) * 1024);
      gl_lds16(W + bOff[r] + k0, (char*)Bs + (r * 4 + w) * 1024);
    }
    __syncthreads();

#pragma unroll
    for (int s = 0; s < 2; ++s) {
      bf16x8 af[4], bfr[4];
#pragma unroll
      for (int mi = 0; mi < 4; ++mi)
        af[mi] = *(const bf16x8*)((char*)As + (wm + mi * 16 + l16) * 128 +
                                  (((quad + 4 * s) ^ x7) << 4));
#pragma unroll
      for (int ni = 0; ni < 4; ++ni)
        bfr[ni] = *(const bf16x8*)((char*)Bs + (wn + ni * 16 + l16) * 128 +
                                   (((quad + 4 * s) ^ x7) << 4));
#pragma unroll
      for (int mi = 0; mi < 4; ++mi)
#pragma unroll
        for (int ni = 0; ni < 4; ++ni)
          acc[mi][ni] = MFMA16(af[mi], bfr[ni], acc[mi][ni]);
    }
    __syncthreads();
  }

  float bcol[4];
#pragma unroll
  for (int ni = 0; ni < 4; ++ni)
    bcol[ni] = (OUT_MODE == 3) ? 0.f : bias[bn + wn + ni * 16 + l16];

#pragma unroll
  for (int mi = 0; mi < 4; ++mi) {
    float brow[4];
    if constexpr (OUT_MODE == 3) {
#pragma unroll
      for (int r = 0; r < 4; ++r) brow[r] = bias[bm + wm + mi * 16 + quad * 4 + r];
    }
#pragma unroll
    for (int ni = 0; ni < 4; ++ni) {
      const int col = bn + wn + ni * 16 + l16;
#pragma unroll
      for (int r = 0; r < 4; ++r) {
        const int row = bm + wm + mi * 16 + quad * 4 + r;
        if constexpr (OUT_MODE == 0) {
          const float val = (acc[mi][ni][r] + bcol[ni]) * oscale;
          ((float*)Cptr)[(size_t)row * DIM + col] = val;
        } else if constexpr (OUT_MODE == 1) {
          const float val = (acc[mi][ni][r] + bcol[ni]) * oscale;
          const int b = row >> LQS;
          const int l = row & (LQ - 1);
          ((bf16*)Cptr)[((((size_t)(b * NH + (col >> 6)) << LQS) + l) << 6) +
                        (col & 63)] = (bf16)val;
        } else {  // OUT_MODE 3: V^T, row = d-index, col = global token
          const float val = acc[mi][ni][r] + brow[r];
          const int bb = col >> 10;
          const int kv = col & 1023;
          ((bf16*)Cptr)[((size_t)(bb * 1024 + row)) * 1024 + kv] = (bf16)val;
        }
      }
    }
  }
}

// ---------------------------------------------------------------------------
// Legacy fp32-input GEMM — fallback when ws is too small for bf16 path.
// ---------------------------------------------------------------------------
template <int OUT_MODE, bool A_BF16>
__global__ __launch_bounds__(256) void gemm_nt(const void* __restrict__ Aptr,
                                               const float* __restrict__ W,
                                               const float* __restrict__ bias,
                                               void* __restrict__ Cptr, int Lq,
                                               float oscale) {
  constexpr int LDT = 72;
  __shared__ bf16 As[128 * LDT];
  __shared__ bf16 Bs[128 * LDT];

  const int bm = blockIdx.x * 128;
  const int bn = blockIdx.y * 128;
  const int tid = threadIdx.x;
  const int w = tid >> 6;
  const int lane = tid & 63;
  const int quad = lane >> 4;
  const int l16 = lane & 15;
  const int wm = (w >> 1) * 64;
  const int wn = (w & 1) * 64;

  f32x4 acc[4][4] = {};

  for (int k0 = 0; k0 < DIM; k0 += 64) {
#pragma unroll
    for (int i = 0; i < 8; ++i) {
      int f = i * 256 + tid;
      int row = f >> 4;
      int c4 = (f & 15) << 2;
      const float4 v = *(const float4*)(W + (size_t)(bn + row) * DIM + k0 + c4);
      bf16x4 bv = {(bf16)v.x, (bf16)v.y, (bf16)v.z, (bf16)v.w};
      *(bf16x4*)&Bs[row * LDT + c4] = bv;
    }
    if constexpr (A_BF16) {
      const bf16* Ab = (const bf16*)Aptr;
#pragma unroll
      for (int i = 0; i < 4; ++i) {
        int f = i * 256 + tid;
        int row = f >> 3;
        int c8 = (f & 7) << 3;
        *(bf16x8*)&As[row * LDT + c8] =
            *(const bf16x8*)(Ab + (size_t)(bm + row) * DIM + k0 + c8);
      }
    } else {
      const float* Af = (const float*)Aptr;
#pragma unroll
      for (int i = 0; i < 8; ++i) {
        int f = i * 256 + tid;
        int row = f >> 4;
        int c4 = (f & 15) << 2;
        const float4 v = *(const float4*)(Af + (size_t)(bm + row) * DIM + k0 + c4);
        bf16x4 av = {(bf16)v.x, (bf16)v.y, (bf16)v.z, (bf16)v.w};
        *(bf16x4*)&As[row * LDT + c4] = av;
      }
    }
    __syncthreads();

#pragma unroll
    for (int sub = 0; sub < 2; ++sub) {
      bf16x8 af[4], bfr[4];
#pragma unroll
      for (int mi = 0; mi < 4; ++mi)
        af[mi] = *(const bf16x8*)&As[(wm + mi * 16 + l16) * LDT + sub * 32 + quad * 8];
#pragma unroll
      for (int ni = 0; ni < 4; ++ni)
        bfr[ni] = *(const bf16x8*)&Bs[(wn + ni * 16 + l16) * LDT + sub * 32 + quad * 8];
#pragma unroll
      for (int mi = 0; mi < 4; ++mi)
#pragma unroll
        for (int ni = 0; ni < 4; ++ni)
          acc[mi][ni] = MFMA16(af[mi], bfr[ni], acc[mi][ni]);
    }
    __syncthreads();
  }

#pragma unroll
  for (int mi = 0; mi < 4; ++mi) {
#pragma unroll
    for (int ni = 0; ni < 4; ++ni) {
      const int col = bn + wn + ni * 16 + l16;
      const float bv = bias[col];
#pragma unroll
      for (int r = 0; r < 4; ++r) {
        const int row = bm + wm + mi * 16 + quad * 4 + r;
        const float val = (acc[mi][ni][r] + bv) * oscale;
        if constexpr (OUT_MODE == 0) {
          ((float*)Cptr)[(size_t)row * DIM + col] = val;
        } else if constexpr (OUT_MODE == 1) {
          const int b = row / Lq;
          const int l = row - b * Lq;
          ((bf16*)Cptr)[((size_t)((b * NH + (col >> 6)) * Lq + l) << 6) + (col & 63)] =
              (bf16)val;
        } else {
          const int b = row >> 10;
          const int kv = row & 1023;
          ((bf16*)Cptr)[(((size_t)(b * NH + (col >> 6)) << 6) + (col & 63)) * 1024 + kv] =
              (bf16)val;
        }
      }
    }
  }
}

// ---------------------------------------------------------------------------
// Flash cross-attention (unchanged): transposed formulation, LDS-staged K/V,
// 128 q rows/block, ones-MFMA denominator.
// ---------------------------------------------------------------------------
__global__ __launch_bounds__(256) void attn_fused(const bf16* __restrict__ Q,
                                                  const bf16* __restrict__ K,
                                                  const bf16* __restrict__ VT,
                                                  bf16* __restrict__ O) {
  __shared__ bf16 Ks[2][64 * 64];
  __shared__ bf16 Vs[2][64 * 64];
  __shared__ bf16 Ps[4 * 16 * 64];

  const int qt = blockIdx.x;
  const int h = blockIdx.y;
  const int b = blockIdx.z;
  const int tid = threadIdx.x;
  const int w = tid >> 6;
  const int lane = tid & 63;
  const int quad = lane >> 4;
  const int l16 = lane & 15;
  const int lr = lane >> 3;
  const int sc8 = (((lane & 7) ^ lr)) << 3;
  const int x7 = l16 & 7;

  const bf16* Qp = Q + ((size_t)(b * NH + h) * 4096 + qt * 128 + w * 32 + l16) * HD + quad * 8;
  const bf16* Kb = K + (size_t)(b * NH + h) * 1024 * HD;
  const bf16* Vb = VT + (size_t)(b * NH + h) * HD * 1024;

  bf16x8 qf[2][2];
#pragma unroll
  for (int g = 0; g < 2; ++g)
#pragma unroll
    for (int s = 0; s < 2; ++s) qf[g][s] = *(const bf16x8*)(Qp + g * 16 * HD + s * 32);

  char* pw = (char*)&Ps[w * 16 * 64];

  f32x4 oacc[2][4] = {};
  f32x4 lacc[2] = {};

  bf16x8 ones;
#pragma unroll
  for (int i = 0; i < 8; ++i) ones[i] = (bf16)1.0f;

  auto stage = [&](int kt, int bi) {
#pragma unroll
    for (int c2 = 0; c2 < 2; ++c2) {
      const int c = c2 * 4 + w;
      gl_lds16(Kb + (size_t)(kt + c * 8 + lr) * HD + sc8, (char*)&Ks[bi][0] + c * 1024);
      gl_lds16(Vb + (size_t)(c * 8 + lr) * 1024 + kt + sc8, (char*)&Vs[bi][0] + c * 1024);
    }
  };

  stage(0, 0);
  int buf = 0;
  for (int kt = 0; kt < 1024; kt += 64) {
    __syncthreads();
    if (kt + 64 < 1024) stage(kt + 64, buf ^ 1);

    bf16x8 kf[4][2];
#pragma unroll
    for (int nt = 0; nt < 4; ++nt)
#pragma unroll
      for (int s = 0; s < 2; ++s)
        kf[nt][s] = *(const bf16x8*)((char*)&Ks[buf][0] + (nt * 16 + l16) * 128 +
                                     (((quad + 4 * s) ^ x7) << 4));

    bf16x8 pf[2][2];
#pragma unroll
    for (int g = 0; g < 2; ++g) {
      __builtin_amdgcn_s_setprio(1);
#pragma unroll
      for (int nt = 0; nt < 4; ++nt) {
        f32x4 a = {0.f, 0.f, 0.f, 0.f};
        a = MFMA16(kf[nt][0], qf[g][0], a);
        a = MFMA16(kf[nt][1], qf[g][1], a);
        bf16x4 pb;
#pragma unroll
        for (int r = 0; r < 4; ++r) pb[r] = (bf16)fast_exp2(a[r]);
        *(bf16x4*)(pw + l16 * 128 + ((nt * 32 + quad * 8) ^ (x7 << 4))) = pb;
      }
      __builtin_amdgcn_s_setprio(0);
#pragma unroll
      for (int s = 0; s < 2; ++s)
        pf[g][s] = *(const bf16x8*)(pw + l16 * 128 + ((s * 64 + quad * 16) ^ (x7 << 4)));
      lacc[g] = MFMA16(ones, pf[g][0], lacc[g]);
      lacc[g] = MFMA16(ones, pf[g][1], lacc[g]);
    }

    __builtin_amdgcn_s_setprio(1);
#pragma unroll
    for (int dt = 0; dt < 4; ++dt) {
      bf16x8 vf0 = *(const bf16x8*)((char*)&Vs[buf][0] + (dt * 16 + l16) * 128 +
                                    ((quad ^ x7) << 4));
      bf16x8 vf1 = *(const bf16x8*)((char*)&Vs[buf][0] + (dt * 16 + l16) * 128 +
                                    ((((quad + 4)) ^ x7) << 4));
      oacc[0][dt] = MFMA16(vf0, pf[0][0], oacc[0][dt]);
      oacc[0][dt] = MFMA16(vf1, pf[0][1], oacc[0][dt]);
      oacc[1][dt] = MFMA16(vf0, pf[1][0], oacc[1][dt]);
      oacc[1][dt] = MFMA16(vf1, pf[1][1], oacc[1][dt]);
    }
    __builtin_amdgcn_s_setprio(0);
    buf ^= 1;
  }

  const float inv[2] = {1.f / lacc[0][0], 1.f / lacc[1][0]};

#pragma unroll
  for (int g = 0; g < 2; ++g) {
    const size_t orow =
        ((size_t)(b * 4096 + qt * 128 + w * 32 + g * 16 + l16)) * DIM + h * 64;
#pragma unroll
    for (int dt = 0; dt < 4; ++dt) {
      bf16x4 ov = {(bf16)(oacc[g][dt][0] * inv[g]), (bf16)(oacc[g][dt][1] * inv[g]),
                   (bf16)(oacc[g][dt][2] * inv[g]), (bf16)(oacc[g][dt][3] * inv[g])};
      *(bf16x4*)(O + orow + dt * 16 + quad * 4) = ov;
    }
  }
}

// ---------------------------------------------------------------------------
extern "C" void kernel_launch(void* const* d_in, const int* in_sizes, int n_in,
                              void* d_out, int out_size, void* d_ws, size_t ws_size,
                              hipStream_t stream) {
  const float* x_broad = (const float*)d_in[0];
  const float* x_low = (const float*)d_in[1];
  const float* Wq = (const float*)d_in[2];
  const float* bq = (const float*)d_in[3];
  const float* Wk = (const float*)d_in[4];
  const float* bk = (const float*)d_in[5];
  const float* Wv = (const float*)d_in[6];
  const float* bv = (const float*)d_in[7];
  const float* Wo = (const float*)d_in[8];
  const float* bo = (const float*)d_in[9];

  constexpr int B = 4, L = 4096, LL = 1024;
  const size_t qBytes = (size_t)B * NH * L * HD * 2;    // 33.55 MB
  const size_t kvBytes = (size_t)B * NH * LL * HD * 2;  //  8.39 MB
  const size_t oBytes = qBytes;                          // 33.55 MB (O / xb_bf alias)
  const size_t xlBytes = kvBytes;                        //  8.39 MB
  const size_t wBytes = (size_t)DIM * DIM * 2;           //  2.10 MB each

  char* ws = (char*)d_ws;
  bf16* Qw = (bf16*)ws;
  bf16* Kw = (bf16*)(ws + qBytes);
  bf16* Vw = (bf16*)(ws + qBytes + kvBytes);
  bf16* Ow = (bf16*)(ws + qBytes + 2 * kvBytes);

  const dim3 blk(256);
  const size_t need = qBytes + 2 * kvBytes + oBytes + xlBytes + 4 * wBytes;

  if (ws_size >= need) {
    // bf16 fast path: Ow region doubles as xb_bf (consumed by Q-proj before attn writes O)
    bf16* xbB = Ow;
    bf16* xlB = (bf16*)(ws + qBytes + 2 * kvBytes + oBytes);
    bf16* WqB = (bf16*)(ws + qBytes + 2 * kvBytes + oBytes + xlBytes);
    bf16* WkB = WqB + (size_t)DIM * DIM;
    bf16* WvB = WkB + (size_t)DIM * DIM;
    bf16* WoB = WvB + (size_t)DIM * DIM;

    hipLaunchKernelGGL(cvt_f32_bf16, dim3(B * L * DIM / 8 / 256), blk, 0, stream,
                       x_broad, xbB, B * L * DIM / 8);
    hipLaunchKernelGGL(cvt_f32_bf16, dim3(B * LL * DIM / 8 / 256), blk, 0, stream,
                       x_low, xlB, B * LL * DIM / 8);
    hipLaunchKernelGGL(cvt_w4, dim3(4 * DIM * DIM / 8 / 256), blk, 0, stream, Wq, Wk,
                       Wv, Wo, WqB);

    // big GEMMs (M=16384): 256^2 phased schedule, counted vmcnt
    hipLaunchKernelGGL((gemm_big<1, L>), dim3(B * L / 256, DIM / 256), dim3(512), 0,
                       stream, xbB, WqB, bq, Qw, SCL2E);
    // small GEMMs (M=4096 / 1024): 128^2 m97 structure
    hipLaunchKernelGGL((gemm_bf16<1, LL>), dim3(B * LL / 128, DIM / 128), blk, 0,
                       stream, xlB, WkB, bk, Kw, 1.0f);
    hipLaunchKernelGGL((gemm_bf16<3, 1>), dim3(DIM / 128, B * LL / 128), blk, 0,
                       stream, WvB, xlB, bv, Vw, 1.0f);
    hipLaunchKernelGGL(attn_fused, dim3(L / 128, NH, B), blk, 0, stream, Qw, Kw, Vw, Ow);
    hipLaunchKernelGGL((gemm_big<0, 1>), dim3(B * L / 256, DIM / 256), dim3(512), 0,
                       stream, Ow, WoB, bo, d_out, 1.0f);
  } else {
    // fallback: fp32-input GEMMs, same attention
    hipLaunchKernelGGL((gemm_nt<1, false>), dim3(B * L / 128, DIM / 128), blk, 0,
                       stream, x_broad, Wq, bq, Qw, L, SCL2E);
    hipLaunchKernelGGL((gemm_nt<1, false>), dim3(B * LL / 128, DIM / 128), blk, 0,
                       stream, x_low, Wk, bk, Kw, LL, 1.0f);
    hipLaunchKernelGGL((gemm_nt<2, false>), dim3(B * LL / 128, DIM / 128), blk, 0,
                       stream, x_low, Wv, bv, Vw, LL, 1.0f);
    hipLaunchKernelGGL(attn_fused, dim3(L / 128, NH, B), blk, 0, stream, Qw, Kw, Vw, Ow);
    hipLaunchKernelGGL((gemm_nt<0, true>), dim3(B * L / 128, DIM / 128), blk, 0,
                       stream, Ow, Wo, bo, d_out, 1, 1.0f);
  }
}

// Round 7
// 381.454 us; speedup vs baseline: 1.0197x; 1.0197x over previous
//
#include <hip/hip_runtime.h>
#include <hip/hip_bf16.h>

typedef __bf16 bf16;
typedef __bf16 bf16x4 __attribute__((ext_vector_type(4)));
typedef __bf16 bf16x8 __attribute__((ext_vector_type(8)));
typedef float f32x4 __attribute__((ext_vector_type(4)));

#define MFMA16(a, b, c) __builtin_amdgcn_mfma_f32_16x16x32_bf16(a, b, c, 0, 0, 0)

constexpr int DIM = 1024;
constexpr int NH = 16;
constexpr int HD = 64;
constexpr float SCALE = 0.125f;
constexpr float L2E = 1.4426950408889634f;
constexpr float SCL2E = SCALE * L2E;  // folded into Q-proj epilogue

constexpr int ilog2(int v) {
  int s = 0;
  while ((1 << s) < v) ++s;
  return s;
}

// raw v_exp_f32 — bypass the denorm-guarded exp2f lowering
__device__ __forceinline__ float fast_exp2(float x) {
  float r;
  asm("v_exp_f32 %0, %1" : "=v"(r) : "v"(x));
  return r;
}

// async global->LDS, 16B per lane; lane i deposits at ldsbase + i*16
__device__ __forceinline__ void gl_lds16(const void* g, void* l) {
  __builtin_amdgcn_global_load_lds((const __attribute__((address_space(1))) void*)g,
                                   (__attribute__((address_space(3))) void*)l, 16, 0, 0);
}

// ---------------------------------------------------------------------------
// Merged fp32->bf16 conversion: x_low (524288 groups of 8) followed by the 4
// weight matrices (4 x 131072 groups). Destinations are CONTIGUOUS in ws
// (xlB then WqB/WkB/WvB/WoB), so one linear output index covers all five.
// x_broad is NOT converted any more — Q-proj reads fp32 directly (gemm_a32).
// ---------------------------------------------------------------------------
__global__ __launch_bounds__(256) void cvt_all(const float* __restrict__ xl,
                                               const float* __restrict__ wq,
                                               const float* __restrict__ wk,
                                               const float* __restrict__ wv,
                                               const float* __restrict__ wo,
                                               bf16* __restrict__ dst) {
  const int i = blockIdx.x * 256 + threadIdx.x;  // 0 .. 1048575
  const float* s;
  int j;
  if (i < 524288) {
    s = xl;
    j = i;
  } else {
    const int k = i - 524288;
    const int g = k >> 17;
    j = k & 131071;
    s = (g == 0) ? wq : (g == 1) ? wk : (g == 2) ? wv : wo;
  }
  const float4 v0 = ((const float4*)s)[j * 2];
  const float4 v1 = ((const float4*)s)[j * 2 + 1];
  bf16x8 o = {(bf16)v0.x, (bf16)v0.y, (bf16)v0.z, (bf16)v0.w,
              (bf16)v1.x, (bf16)v1.y, (bf16)v1.z, (bf16)v1.w};
  ((bf16x8*)dst)[i] = o;
}

// ---------------------------------------------------------------------------
// Q-proj GEMM with FUSED A conversion: A is fp32 (x_broad read directly,
// no cvt pass), reg-staged fp32->bf16 into swizzled LDS; W stays on the
// global_load_lds fast path. Otherwise identical to the m97 128^2 structure.
// A-staging: 4 passes; thread handles row = p*32 + (tid>>3), 8 fp32 at
// chunk g = tid&7; written to LDS slot g ^ (row&7) (matches frag-read swz).
// ---------------------------------------------------------------------------
template <int OUT_MODE, int LQ>
__global__ __launch_bounds__(256) void gemm_a32(const float* __restrict__ A32,
                                                const bf16* __restrict__ W,
                                                const float* __restrict__ bias,
                                                void* __restrict__ Cptr,
                                                float oscale) {
  constexpr int LQS = ilog2(LQ);
  __shared__ bf16 As[128 * 64];
  __shared__ bf16 Bs[128 * 64];

  const int bm = blockIdx.x * 128;
  const int bn = blockIdx.y * 128;
  const int tid = threadIdx.x;
  const int w = tid >> 6;
  const int lane = tid & 63;
  const int quad = lane >> 4;
  const int l16 = lane & 15;
  const int wm = (w >> 1) * 64;
  const int wn = (w & 1) * 64;
  const int lr = lane >> 3;
  const int sc8 = (((lane & 7) ^ lr)) << 3;
  const int x7 = l16 & 7;

  size_t bOff[4];
#pragma unroll
  for (int r = 0; r < 4; ++r)
    bOff[r] = (size_t)(bn + (r * 4 + w) * 8 + lr) * DIM + sc8;

  // A-staging geometry (reg-staged)
  const int arow = tid >> 3;                       // 0..31 (row within pass)
  const int ag = tid & 7;                          // chunk 0..7
  const int asw = (ag ^ (arow & 7)) << 4;          // swizzled byte slot
  const float* Ab = A32 + (size_t)(bm + arow) * DIM + ag * 8;

  f32x4 acc[4][4] = {};

  for (int k0 = 0; k0 < DIM; k0 += 64) {
#pragma unroll
    for (int r = 0; r < 4; ++r)
      gl_lds16(W + bOff[r] + k0, (char*)Bs + (r * 4 + w) * 1024);
#pragma unroll
    for (int p = 0; p < 4; ++p) {
      const float* src = Ab + (size_t)(p * 32) * DIM + k0;
      const float4 v0 = *(const float4*)(src);
      const float4 v1 = *(const float4*)(src + 4);
      bf16x8 o = {(bf16)v0.x, (bf16)v0.y, (bf16)v0.z, (bf16)v0.w,
                  (bf16)v1.x, (bf16)v1.y, (bf16)v1.z, (bf16)v1.w};
      *(bf16x8*)((char*)As + (p * 32 + arow) * 128 + asw) = o;
    }
    __syncthreads();  // drains gl_lds16 (vmcnt) + ds_writes (lgkm)

#pragma unroll
    for (int s = 0; s < 2; ++s) {
      bf16x8 af[4], bfr[4];
#pragma unroll
      for (int mi = 0; mi < 4; ++mi)
        af[mi] = *(const bf16x8*)((char*)As + (wm + mi * 16 + l16) * 128 +
                                  (((quad + 4 * s) ^ x7) << 4));
#pragma unroll
      for (int ni = 0; ni < 4; ++ni)
        bfr[ni] = *(const bf16x8*)((char*)Bs + (wn + ni * 16 + l16) * 128 +
                                   (((quad + 4 * s) ^ x7) << 4));
#pragma unroll
      for (int mi = 0; mi < 4; ++mi)
#pragma unroll
        for (int ni = 0; ni < 4; ++ni)
          acc[mi][ni] = MFMA16(af[mi], bfr[ni], acc[mi][ni]);
    }
    __syncthreads();
  }

  float bcol[4];
#pragma unroll
  for (int ni = 0; ni < 4; ++ni) bcol[ni] = bias[bn + wn + ni * 16 + l16];

#pragma unroll
  for (int mi = 0; mi < 4; ++mi) {
#pragma unroll
    for (int ni = 0; ni < 4; ++ni) {
      const int col = bn + wn + ni * 16 + l16;
#pragma unroll
      for (int r = 0; r < 4; ++r) {
        const int row = bm + wm + mi * 16 + quad * 4 + r;
        const float val = (acc[mi][ni][r] + bcol[ni]) * oscale;
        if constexpr (OUT_MODE == 0) {
          ((float*)Cptr)[(size_t)row * DIM + col] = val;
        } else {
          const int b = row >> LQS;
          const int l = row & (LQ - 1);
          ((bf16*)Cptr)[((((size_t)(b * NH + (col >> 6)) << LQS) + l) << 6) +
                        (col & 63)] = (bf16)val;
        }
      }
    }
  }
}

// ---------------------------------------------------------------------------
// bf16 NT GEMM, m97 structure (128^2).
// OUT_MODE 0: fp32 row-major; 1: bf16 head-major; 3: V^T flipped (bias ROW).
// ---------------------------------------------------------------------------
template <int OUT_MODE, int LQ>
__global__ __launch_bounds__(256) void gemm_bf16(const bf16* __restrict__ A,
                                                 const bf16* __restrict__ W,
                                                 const float* __restrict__ bias,
                                                 void* __restrict__ Cptr,
                                                 float oscale) {
  constexpr int LQS = ilog2(LQ);
  __shared__ bf16 As[128 * 64];
  __shared__ bf16 Bs[128 * 64];

  const int bm = blockIdx.x * 128;
  const int bn = blockIdx.y * 128;
  const int tid = threadIdx.x;
  const int w = tid >> 6;
  const int lane = tid & 63;
  const int quad = lane >> 4;
  const int l16 = lane & 15;
  const int wm = (w >> 1) * 64;
  const int wn = (w & 1) * 64;
  const int lr = lane >> 3;
  const int sc8 = (((lane & 7) ^ lr)) << 3;
  const int x7 = l16 & 7;

  size_t aOff[4], bOff[4];
#pragma unroll
  for (int r = 0; r < 4; ++r) {
    const int rowt = (r * 4 + w) * 8 + lr;
    aOff[r] = (size_t)(bm + rowt) * DIM + sc8;
    bOff[r] = (size_t)(bn + rowt) * DIM + sc8;
  }

  f32x4 acc[4][4] = {};

  for (int k0 = 0; k0 < DIM; k0 += 64) {
#pragma unroll
    for (int r = 0; r < 4; ++r) {
      gl_lds16(A + aOff[r] + k0, (char*)As + (r * 4 + w) * 1024);
      gl_lds16(W + bOff[r] + k0, (char*)Bs + (r * 4 + w) * 1024);
    }
    __syncthreads();

#pragma unroll
    for (int s = 0; s < 2; ++s) {
      bf16x8 af[4], bfr[4];
#pragma unroll
      for (int mi = 0; mi < 4; ++mi)
        af[mi] = *(const bf16x8*)((char*)As + (wm + mi * 16 + l16) * 128 +
                                  (((quad + 4 * s) ^ x7) << 4));
#pragma unroll
      for (int ni = 0; ni < 4; ++ni)
        bfr[ni] = *(const bf16x8*)((char*)Bs + (wn + ni * 16 + l16) * 128 +
                                   (((quad + 4 * s) ^ x7) << 4));
#pragma unroll
      for (int mi = 0; mi < 4; ++mi)
#pragma unroll
        for (int ni = 0; ni < 4; ++ni)
          acc[mi][ni] = MFMA16(af[mi], bfr[ni], acc[mi][ni]);
    }
    __syncthreads();
  }

  float bcol[4];
#pragma unroll
  for (int ni = 0; ni < 4; ++ni)
    bcol[ni] = (OUT_MODE == 3) ? 0.f : bias[bn + wn + ni * 16 + l16];

#pragma unroll
  for (int mi = 0; mi < 4; ++mi) {
    float brow[4];
    if constexpr (OUT_MODE == 3) {
#pragma unroll
      for (int r = 0; r < 4; ++r) brow[r] = bias[bm + wm + mi * 16 + quad * 4 + r];
    }
#pragma unroll
    for (int ni = 0; ni < 4; ++ni) {
      const int col = bn + wn + ni * 16 + l16;
#pragma unroll
      for (int r = 0; r < 4; ++r) {
        const int row = bm + wm + mi * 16 + quad * 4 + r;
        if constexpr (OUT_MODE == 0) {
          const float val = (acc[mi][ni][r] + bcol[ni]) * oscale;
          ((float*)Cptr)[(size_t)row * DIM + col] = val;
        } else if constexpr (OUT_MODE == 1) {
          const float val = (acc[mi][ni][r] + bcol[ni]) * oscale;
          const int b = row >> LQS;
          const int l = row & (LQ - 1);
          ((bf16*)Cptr)[((((size_t)(b * NH + (col >> 6)) << LQS) + l) << 6) +
                        (col & 63)] = (bf16)val;
        } else {  // OUT_MODE 3: V^T, row = d-index, col = global token
          const float val = acc[mi][ni][r] + brow[r];
          const int bb = col >> 10;
          const int kv = col & 1023;
          ((bf16*)Cptr)[((size_t)(bb * 1024 + row)) * 1024 + kv] = (bf16)val;
        }
      }
    }
  }
}

// ---------------------------------------------------------------------------
// Legacy fp32-input GEMM — fallback when ws is too small for bf16 path.
// ---------------------------------------------------------------------------
template <int OUT_MODE, bool A_BF16>
__global__ __launch_bounds__(256) void gemm_nt(const void* __restrict__ Aptr,
                                               const float* __restrict__ W,
                                               const float* __restrict__ bias,
                                               void* __restrict__ Cptr, int Lq,
                                               float oscale) {
  constexpr int LDT = 72;
  __shared__ bf16 As[128 * LDT];
  __shared__ bf16 Bs[128 * LDT];

  const int bm = blockIdx.x * 128;
  const int bn = blockIdx.y * 128;
  const int tid = threadIdx.x;
  const int w = tid >> 6;
  const int lane = tid & 63;
  const int quad = lane >> 4;
  const int l16 = lane & 15;
  const int wm = (w >> 1) * 64;
  const int wn = (w & 1) * 64;

  f32x4 acc[4][4] = {};

  for (int k0 = 0; k0 < DIM; k0 += 64) {
#pragma unroll
    for (int i = 0; i < 8; ++i) {
      int f = i * 256 + tid;
      int row = f >> 4;
      int c4 = (f & 15) << 2;
      const float4 v = *(const float4*)(W + (size_t)(bn + row) * DIM + k0 + c4);
      bf16x4 bv = {(bf16)v.x, (bf16)v.y, (bf16)v.z, (bf16)v.w};
      *(bf16x4*)&Bs[row * LDT + c4] = bv;
    }
    if constexpr (A_BF16) {
      const bf16* Ab = (const bf16*)Aptr;
#pragma unroll
      for (int i = 0; i < 4; ++i) {
        int f = i * 256 + tid;
        int row = f >> 3;
        int c8 = (f & 7) << 3;
        *(bf16x8*)&As[row * LDT + c8] =
            *(const bf16x8*)(Ab + (size_t)(bm + row) * DIM + k0 + c8);
      }
    } else {
      const float* Af = (const float*)Aptr;
#pragma unroll
      for (int i = 0; i < 8; ++i) {
        int f = i * 256 + tid;
        int row = f >> 4;
        int c4 = (f & 15) << 2;
        const float4 v = *(const float4*)(Af + (size_t)(bm + row) * DIM + k0 + c4);
        bf16x4 av = {(bf16)v.x, (bf16)v.y, (bf16)v.z, (bf16)v.w};
        *(bf16x4*)&As[row * LDT + c4] = av;
      }
    }
    __syncthreads();

#pragma unroll
    for (int sub = 0; sub < 2; ++sub) {
      bf16x8 af[4], bfr[4];
#pragma unroll
      for (int mi = 0; mi < 4; ++mi)
        af[mi] = *(const bf16x8*)&As[(wm + mi * 16 + l16) * LDT + sub * 32 + quad * 8];
#pragma unroll
      for (int ni = 0; ni < 4; ++ni)
        bfr[ni] = *(const bf16x8*)&Bs[(wn + ni * 16 + l16) * LDT + sub * 32 + quad * 8];
#pragma unroll
      for (int mi = 0; mi < 4; ++mi)
#pragma unroll
        for (int ni = 0; ni < 4; ++ni)
          acc[mi][ni] = MFMA16(af[mi], bfr[ni], acc[mi][ni]);
    }
    __syncthreads();
  }

#pragma unroll
  for (int mi = 0; mi < 4; ++mi) {
#pragma unroll
    for (int ni = 0; ni < 4; ++ni) {
      const int col = bn + wn + ni * 16 + l16;
      const float bv = bias[col];
#pragma unroll
      for (int r = 0; r < 4; ++r) {
        const int row = bm + wm + mi * 16 + quad * 4 + r;
        const float val = (acc[mi][ni][r] + bv) * oscale;
        if constexpr (OUT_MODE == 0) {
          ((float*)Cptr)[(size_t)row * DIM + col] = val;
        } else if constexpr (OUT_MODE == 1) {
          const int b = row / Lq;
          const int l = row - b * Lq;
          ((bf16*)Cptr)[((size_t)((b * NH + (col >> 6)) * Lq + l) << 6) + (col & 63)] =
              (bf16)val;
        } else {
          const int b = row >> 10;
          const int kv = row & 1023;
          ((bf16*)Cptr)[(((size_t)(b * NH + (col >> 6)) << 6) + (col & 63)) * 1024 + kv] =
              (bf16)val;
        }
      }
    }
  }
}

// ---------------------------------------------------------------------------
// Flash cross-attention (unchanged): transposed formulation, LDS-staged K/V,
// 128 q rows/block, ones-MFMA denominator.
// ---------------------------------------------------------------------------
__global__ __launch_bounds__(256) void attn_fused(const bf16* __restrict__ Q,
                                                  const bf16* __restrict__ K,
                                                  const bf16* __restrict__ VT,
                                                  bf16* __restrict__ O) {
  __shared__ bf16 Ks[2][64 * 64];
  __shared__ bf16 Vs[2][64 * 64];
  __shared__ bf16 Ps[4 * 16 * 64];

  const int qt = blockIdx.x;
  const int h = blockIdx.y;
  const int b = blockIdx.z;
  const int tid = threadIdx.x;
  const int w = tid >> 6;
  const int lane = tid & 63;
  const int quad = lane >> 4;
  const int l16 = lane & 15;
  const int lr = lane >> 3;
  const int sc8 = (((lane & 7) ^ lr)) << 3;
  const int x7 = l16 & 7;

  const bf16* Qp = Q + ((size_t)(b * NH + h) * 4096 + qt * 128 + w * 32 + l16) * HD + quad * 8;
  const bf16* Kb = K + (size_t)(b * NH + h) * 1024 * HD;
  const bf16* Vb = VT + (size_t)(b * NH + h) * HD * 1024;

  bf16x8 qf[2][2];
#pragma unroll
  for (int g = 0; g < 2; ++g)
#pragma unroll
    for (int s = 0; s < 2; ++s) qf[g][s] = *(const bf16x8*)(Qp + g * 16 * HD + s * 32);

  char* pw = (char*)&Ps[w * 16 * 64];

  f32x4 oacc[2][4] = {};
  f32x4 lacc[2] = {};

  bf16x8 ones;
#pragma unroll
  for (int i = 0; i < 8; ++i) ones[i] = (bf16)1.0f;

  auto stage = [&](int kt, int bi) {
#pragma unroll
    for (int c2 = 0; c2 < 2; ++c2) {
      const int c = c2 * 4 + w;
      gl_lds16(Kb + (size_t)(kt + c * 8 + lr) * HD + sc8, (char*)&Ks[bi][0] + c * 1024);
      gl_lds16(Vb + (size_t)(c * 8 + lr) * 1024 + kt + sc8, (char*)&Vs[bi][0] + c * 1024);
    }
  };

  stage(0, 0);
  int buf = 0;
  for (int kt = 0; kt < 1024; kt += 64) {
    __syncthreads();
    if (kt + 64 < 1024) stage(kt + 64, buf ^ 1);

    bf16x8 kf[4][2];
#pragma unroll
    for (int nt = 0; nt < 4; ++nt)
#pragma unroll
      for (int s = 0; s < 2; ++s)
        kf[nt][s] = *(const bf16x8*)((char*)&Ks[buf][0] + (nt * 16 + l16) * 128 +
                                     (((quad + 4 * s) ^ x7) << 4));

    bf16x8 pf[2][2];
#pragma unroll
    for (int g = 0; g < 2; ++g) {
      __builtin_amdgcn_s_setprio(1);
#pragma unroll
      for (int nt = 0; nt < 4; ++nt) {
        f32x4 a = {0.f, 0.f, 0.f, 0.f};
        a = MFMA16(kf[nt][0], qf[g][0], a);
        a = MFMA16(kf[nt][1], qf[g][1], a);
        bf16x4 pb;
#pragma unroll
        for (int r = 0; r < 4; ++r) pb[r] = (bf16)fast_exp2(a[r]);
        *(bf16x4*)(pw + l16 * 128 + ((nt * 32 + quad * 8) ^ (x7 << 4))) = pb;
      }
      __builtin_amdgcn_s_setprio(0);
#pragma unroll
      for (int s = 0; s < 2; ++s)
        pf[g][s] = *(const bf16x8*)(pw + l16 * 128 + ((s * 64 + quad * 16) ^ (x7 << 4)));
      lacc[g] = MFMA16(ones, pf[g][0], lacc[g]);
      lacc[g] = MFMA16(ones, pf[g][1], lacc[g]);
    }

    __builtin_amdgcn_s_setprio(1);
#pragma unroll
    for (int dt = 0; dt < 4; ++dt) {
      bf16x8 vf0 = *(const bf16x8*)((char*)&Vs[buf][0] + (dt * 16 + l16) * 128 +
                                    ((quad ^ x7) << 4));
      bf16x8 vf1 = *(const bf16x8*)((char*)&Vs[buf][0] + (dt * 16 + l16) * 128 +
                                    ((((quad + 4)) ^ x7) << 4));
      oacc[0][dt] = MFMA16(vf0, pf[0][0], oacc[0][dt]);
      oacc[0][dt] = MFMA16(vf1, pf[0][1], oacc[0][dt]);
      oacc[1][dt] = MFMA16(vf0, pf[1][0], oacc[1][dt]);
      oacc[1][dt] = MFMA16(vf1, pf[1][1], oacc[1][dt]);
    }
    __builtin_amdgcn_s_setprio(0);
    buf ^= 1;
  }

  const float inv[2] = {1.f / lacc[0][0], 1.f / lacc[1][0]};

#pragma unroll
  for (int g = 0; g < 2; ++g) {
    const size_t orow =
        ((size_t)(b * 4096 + qt * 128 + w * 32 + g * 16 + l16)) * DIM + h * 64;
#pragma unroll
    for (int dt = 0; dt < 4; ++dt) {
      bf16x4 ov = {(bf16)(oacc[g][dt][0] * inv[g]), (bf16)(oacc[g][dt][1] * inv[g]),
                   (bf16)(oacc[g][dt][2] * inv[g]), (bf16)(oacc[g][dt][3] * inv[g])};
      *(bf16x4*)(O + orow + dt * 16 + quad * 4) = ov;
    }
  }
}

// ---------------------------------------------------------------------------
extern "C" void kernel_launch(void* const* d_in, const int* in_sizes, int n_in,
                              void* d_out, int out_size, void* d_ws, size_t ws_size,
                              hipStream_t stream) {
  const float* x_broad = (const float*)d_in[0];
  const float* x_low = (const float*)d_in[1];
  const float* Wq = (const float*)d_in[2];
  const float* bq = (const float*)d_in[3];
  const float* Wk = (const float*)d_in[4];
  const float* bk = (const float*)d_in[5];
  const float* Wv = (const float*)d_in[6];
  const float* bv = (const float*)d_in[7];
  const float* Wo = (const float*)d_in[8];
  const float* bo = (const float*)d_in[9];

  constexpr int B = 4, L = 4096, LL = 1024;
  const size_t qBytes = (size_t)B * NH * L * HD * 2;    // 33.55 MB
  const size_t kvBytes = (size_t)B * NH * LL * HD * 2;  //  8.39 MB
  const size_t oBytes = qBytes;                          // 33.55 MB
  const size_t xlBytes = kvBytes;                        //  8.39 MB
  const size_t wBytes = (size_t)DIM * DIM * 2;           //  2.10 MB each

  char* ws = (char*)d_ws;
  bf16* Qw = (bf16*)ws;
  bf16* Kw = (bf16*)(ws + qBytes);
  bf16* Vw = (bf16*)(ws + qBytes + kvBytes);
  bf16* Ow = (bf16*)(ws + qBytes + 2 * kvBytes);

  const dim3 blk(256);
  const size_t need = qBytes + 2 * kvBytes + oBytes + xlBytes + 4 * wBytes;

  if (ws_size >= need) {
    bf16* xlB = (bf16*)(ws + qBytes + 2 * kvBytes + oBytes);
    bf16* WqB = (bf16*)(ws + qBytes + 2 * kvBytes + oBytes + xlBytes);
    bf16* WkB = WqB + (size_t)DIM * DIM;
    bf16* WvB = WkB + (size_t)DIM * DIM;
    bf16* WoB = WvB + (size_t)DIM * DIM;

    // one conversion pass: x_low + 4 weights (contiguous dst starting at xlB)
    hipLaunchKernelGGL(cvt_all, dim3((524288 + 4 * 131072) / 256), blk, 0, stream,
                       x_low, Wq, Wk, Wv, Wo, xlB);

    // Q-proj: fp32 A read directly (fused conversion), softmax scale folded
    hipLaunchKernelGGL((gemm_a32<1, L>), dim3(B * L / 128, DIM / 128), blk, 0, stream,
                       x_broad, WqB, bq, Qw, SCL2E);
    hipLaunchKernelGGL((gemm_bf16<1, LL>), dim3(B * LL / 128, DIM / 128), blk, 0,
                       stream, xlB, WkB, bk, Kw, 1.0f);
    // V^T via flipped orientation: A = Wv (rows=d), B = x_low (rows=token)
    hipLaunchKernelGGL((gemm_bf16<3, 1>), dim3(DIM / 128, B * LL / 128), blk, 0,
                       stream, WvB, xlB, bv, Vw, 1.0f);
    hipLaunchKernelGGL(attn_fused, dim3(L / 128, NH, B), blk, 0, stream, Qw, Kw, Vw, Ow);
    hipLaunchKernelGGL((gemm_bf16<0, 1>), dim3(B * L / 128, DIM / 128), blk, 0, stream,
                       Ow, WoB, bo, d_out, 1.0f);
  } else {
    // fallback: fp32-input GEMMs, same attention
    hipLaunchKernelGGL((gemm_nt<1, false>), dim3(B * L / 128, DIM / 128), blk, 0,
                       stream, x_broad, Wq, bq, Qw, L, SCL2E);
    hipLaunchKernelGGL((gemm_nt<1, false>), dim3(B * LL / 128, DIM / 128), blk, 0,
                       stream, x_low, Wk, bk, Kw, LL, 1.0f);
    hipLaunchKernelGGL((gemm_nt<2, false>), dim3(B * LL / 128, DIM / 128), blk, 0,
                       stream, x_low, Wv, bv, Vw, LL, 1.0f);
    hipLaunchKernelGGL(attn_fused, dim3(L / 128, NH, B), blk, 0, stream, Qw, Kw, Vw, Ow);
    hipLaunchKernelGGL((gemm_nt<0, true>), dim3(B * L / 128, DIM / 128), blk, 0,
                       stream, Ow, Wo, bo, d_out, 1, 1.0f);
  }
}